// Round 16
// baseline (62.874 us; speedup 1.0000x reference)
//
#include <hip/hip_runtime.h>

typedef unsigned int   u32;
typedef unsigned short u16;
typedef _Float16       f16;

using f16x8  = __attribute__((ext_vector_type(8)))  _Float16;
using f16x2  = __attribute__((ext_vector_type(2)))  _Float16;
using f32x16 = __attribute__((ext_vector_type(16))) float;

#define KEEP(x) asm volatile("" : "+v"(x))

// ---- merged prep: [bid<2560] x transpose+sums; [else] W0/W1 k-panel ----
__global__ __launch_bounds__(256)
void prep(const float* __restrict__ x,
          const float* __restrict__ W0, const float* __restrict__ W1,
          f16* __restrict__ xt, f16* __restrict__ W0p, f16* __restrict__ W1p,
          float* __restrict__ out){
  __shared__ char shm[33920];
  const int tid = threadIdx.x;
  if (blockIdx.x < 2560){
    float (*tile)[33] = (float(*)[33])shm;
    const int r0 = blockIdx.x << 5;
    const int c  = tid & 31;
    const int rp = tid >> 5;
#pragma unroll
    for (int p = 0; p < 4; ++p){
      const int r = (p << 3) + rp;
      float v = x[(size_t)(r0 + r) * 32 + c];
      tile[r][c] = v;
      float s = v;
#pragma unroll
      for (int off = 16; off > 0; off >>= 1) s += __shfl_xor(s, off, 32);
      if (c == 0){
        const int row = r0 + r;            // = b*40 + f
        out[(size_t)(row / 40) * 168 + (row % 40)] = s;
      }
    }
    __syncthreads();
#pragma unroll
    for (int p = 0; p < 4; ++p){
      const int dd = (p << 3) + rp;
      xt[(size_t)dd * 81920 + r0 + c] = (f16)tile[c][dd];
    }
  } else {
    u16* t = (u16*)shm;
    int kb = blockIdx.x - 2560;
    const float* in; f16* outp; int K;
    if (kb < 200){ in = W0; outp = W0p; K = 1600; }
    else         { kb -= 200; in = W1; outp = W1p; K = 2560; }
    const int kbase = kb << 3;
#pragma unroll 4
    for (int i = 0; i < 64; ++i){
      const int idx = tid + (i << 8);
      const int o   = idx >> 8;
      const int rem = idx & 255;
      const int e   = rem >> 5;
      const int dd  = rem & 31;
      const float v = in[(size_t)o * (K * 32) + (size_t)(kbase + e) * 32 + dd];
      union { f16 h; u16 u; } cv; cv.h = (f16)v;
      t[dd * 530 + o * 8 + e] = cv.u;
    }
    __syncthreads();
    const u32* t32 = (const u32*)t;
    u32* o32 = (u32*)outp;
    const int obase = kb << 8;
#pragma unroll 4
    for (int i = 0; i < 32; ++i){
      const int idx = tid + (i << 8);
      const int dd  = idx >> 8;
      const int rem = idx & 255;
      o32[(size_t)dd * (K * 32) + obase + rem] = t32[dd * 265 + rem];
    }
  }
}

// ---- fused CIN: barrier-free K-split streaming GEMM ----
// Block: 64 rows x 64 cols x one d, 4 waves = (wc col-half) x (kh K-half).
// Wave: 64 rows x 32 cols x K/2, BK=80 tiles, B streamed global->regs
// (dbuf B0/B1, compiler-auto vmcnt).  NO barriers in the K loops.
// Phase boundary: kh=1 dumps acc to LDS f32; kh=0 reduces + bias + relu.
__global__ __launch_bounds__(256, 2)
void cin_fused(const f16* __restrict__ xt,     // [32][2048*40] f16
               const f16* __restrict__ W0p,    // [32][200][64][8] f16
               const f16* __restrict__ W1p,    // [32][320][64][8] f16
               const float* __restrict__ b0v, const float* __restrict__ b1v,
               f16* __restrict__ x1s,          // [2048][32][64] f16
               f16* __restrict__ y2s){         // [2048][32][64] f16
  constexpr int XOFF = 16896;           // red[2][64][33] f32 below; x0/x1 overlay

  const int bid = blockIdx.x;
  const int d   = ((bid & 7) << 2) | ((bid >> 3) & 3);   // XCD-local d groups
  const int b0  = (bid >> 5) << 6;      // 32 b-tiles of 64 rows
  const int tid = threadIdx.x;
  const int wv  = tid >> 6;
  const int kh  = wv >> 1;              // K half
  const int wc  = wv & 1;               // col half (32 cols)
  const int l   = tid & 63;
  const int hi  = l >> 5;               // k-run parity within MFMA
  const int lr  = l & 31;

  __shared__ char smem[26112];

  const f16* gW0 = W0p + (size_t)d * 102400;
  const f16* gW1 = W1p + (size_t)d * 163840;
  const int lane_off = hi * 512 + ((wc << 5) + lr) * 8;  // f16 units

  f16x8 B0[5], B1[5];

#define LOADB(B, GP, TT) do { \
    _Pragma("unroll") \
    for (int mi_ = 0; mi_ < 5; ++mi_) \
      (B)[mi_] = *(const f16x8*)((GP) + (size_t)(TT) * 5120 + mi_ * 1024); \
    __builtin_amdgcn_sched_barrier(0); \
  } while (0)

  const f16* g1 = gW0 + kh * 51200 + lane_off;
  LOADB(B0, g1, 0);                     // phase-1 tile 0 in flight

  { // stage x0 tile: 64 rows * 80B -> stride 96B
    const uint4* src = (const uint4*)(xt + (size_t)d * 81920 + (size_t)b0 * 40);
#pragma unroll
    for (int it = 0; it < 2; ++it){
      const int idx = tid + (it << 8);
      if (idx < 320){
        const int r = idx / 5, c = idx - r * 5;
        *(uint4*)(smem + XOFF + r * 96 + c * 16) = src[idx];
      }
    }
  }
  __syncthreads();

  const char* x0row = smem + XOFF + lr * 96;    // + m*3072 per strip
  const char* x1row = smem + XOFF + lr * 144;   // + m*4608 per strip
  const int   col = (wc << 5) + lr;
  const float bv1 = b0v[col];
  const float bv2 = b1v[col];

  // sl[m][s] = x0 f-block (s+hi)%5 of strip-m row (pinned in VGPRs)
  f16x8 sl[2][5];
#pragma unroll
  for (int m = 0; m < 2; ++m){
    const char* xe = x0row + m * 3072 + hi * 16;
#pragma unroll
    for (int t = 0; t < 4; ++t) sl[m][t] = *(const f16x8*)(xe + t * 16);
    sl[m][4] = *(const f16x8*)(x0row + m * 3072 + (hi ? 0 : 64));
  }
  KEEP(sl[0][0]); KEEP(sl[0][1]); KEEP(sl[0][2]); KEEP(sl[0][3]); KEEP(sl[0][4]);
  KEEP(sl[1][0]); KEEP(sl[1][1]); KEEP(sl[1][2]); KEEP(sl[1][3]); KEEP(sl[1][4]);

  const f32x16 fz = {0,0,0,0,0,0,0,0,0,0,0,0,0,0,0,0};
  f32x16 accA = fz, accB = fz;          // strip 0 / strip 1 chains

  // BK=80: k-run r8 = 2mi+hi (mod tile); slot (2mi)%5; h-elem: mi<2 x,
  // mi>2 y, mi==2 hi?y:x.  h pair per tile = {hbase+2t, hbase+2t+1}.
  static constexpr int SI[5] = {0, 2, 4, 1, 3};

#define COMP(B, XB, TT, HOFF, MS) do { \
    const f16x2 xhp0 = *(const f16x2*)((XB) + (HOFF) + (TT) * 4); \
    const f16x2 xhp1 = *(const f16x2*)((XB) + (HOFF) + (TT) * 4 + (MS)); \
    __builtin_amdgcn_s_setprio(1); \
    _Pragma("unroll") \
    for (int mi = 0; mi < 5; ++mi){ \
      const f16x8 bf = (B)[mi]; \
      const f16 xa0 = (mi < 2) ? xhp0[0] : (mi > 2) ? xhp0[1] : (hi ? xhp0[1] : xhp0[0]); \
      const f16 xa1 = (mi < 2) ? xhp1[0] : (mi > 2) ? xhp1[1] : (hi ? xhp1[1] : xhp1[0]); \
      accA = __builtin_amdgcn_mfma_f32_32x32x16_f16(sl[0][SI[mi]] * xa0, bf, accA, 0, 0, 0); \
      accB = __builtin_amdgcn_mfma_f32_32x32x16_f16(sl[1][SI[mi]] * xa1, bf, accB, 0, 0, 0); \
    } \
    __builtin_amdgcn_s_setprio(0); \
  } while (0)

  // ---------------- phase 1: xk = x0, 10 tiles per wave (K/2=800) ----------------
  {
    const int hoff = kh * 40;           // (kh*20 h values) * 2B
    for (int t = 0; t < 10; t += 2){
      LOADB(B1, g1, t + 1);
      COMP(B0, x0row, t, hoff, 3072);
      LOADB(B0, g1, t + 2);             // over-read at t=8 is ws-safe
      COMP(B1, x0row, t + 1, hoff, 3072);
    }
  }

  // ---- phase boundary: kh-reduce, bias+relu, x1 -> LDS + global ----
  float* redp = (float*)(smem + wc * 8448);     // [64][33] f32 per col-half
  u16*   x1w  = (u16*)(smem + XOFF);            // [64][72] u16 (overlays x0)
  if (kh == 1){
#pragma unroll
    for (int m = 0; m < 2; ++m)
#pragma unroll
      for (int reg = 0; reg < 16; ++reg){
        const int row = (m << 5) + (reg & 3) + ((reg >> 2) << 3) + (hi << 2);
        redp[row * 33 + lr] = (m ? accB[reg] : accA[reg]);
      }
  }
  __syncthreads();
  if (kh == 0){
#pragma unroll
    for (int m = 0; m < 2; ++m)
#pragma unroll
      for (int reg = 0; reg < 16; ++reg){
        const int row = (m << 5) + (reg & 3) + ((reg >> 2) << 3) + (hi << 2);
        float v = (m ? accB[reg] : accA[reg]) + redp[row * 33 + lr] + bv1;
        v = v > 0.f ? v : 0.f;
        union { f16 h; u16 u; } cv; cv.h = (f16)v;
        x1w[row * 72 + col] = cv.u;
      }
  }
  accA = fz; accB = fz;
  const f16* g2 = gW1 + kh * 81920 + lane_off;
  LOADB(B0, g2, 0);                     // phase-2 tile 0 in flight
  __syncthreads();                      // x1 tile complete + red free

  { // x1 partial store: 64 rows x 8 chunks = 512 granules, coalesced 16B
#pragma unroll
    for (int it = 0; it < 2; ++it){
      const int u   = tid + (it << 8);
      const int row = u >> 3, ch = u & 7;
      const f16x8 vv = *(const f16x8*)((const char*)x1w + row * 144 + ch * 16);
      *(f16x8*)(x1s + (size_t)(b0 + row) * 2048 + d * 64 + ch * 8) = vv;
    }
  }

  // ---------------- phase 2: xk = x1, 16 tiles per wave (K/2=1280) ----------------
  {
    const int hoff = kh * 64;           // (kh*32 h values) * 2B
    for (int t = 0; t < 16; t += 2){
      LOADB(B1, g2, t + 1);
      COMP(B0, x1row, t, hoff, 4608);
      LOADB(B0, g2, t + 2);             // over-read at t=14 is ws-safe
      COMP(B1, x1row, t + 1, hoff, 4608);
    }
  }

  // ---- epilogue 2: kh-reduce, bias+relu, y2 -> LDS -> global ----
  if (kh == 1){
#pragma unroll
    for (int m = 0; m < 2; ++m)
#pragma unroll
      for (int reg = 0; reg < 16; ++reg){
        const int row = (m << 5) + (reg & 3) + ((reg >> 2) << 3) + (hi << 2);
        redp[row * 33 + lr] = (m ? accB[reg] : accA[reg]);
      }
  }
  __syncthreads();
  if (kh == 0){
#pragma unroll
    for (int m = 0; m < 2; ++m)
#pragma unroll
      for (int reg = 0; reg < 16; ++reg){
        const int row = (m << 5) + (reg & 3) + ((reg >> 2) << 3) + (hi << 2);
        float v = (m ? accB[reg] : accA[reg]) + redp[row * 33 + lr] + bv2;
        v = v > 0.f ? v : 0.f;
        union { f16 h; u16 u; } cv; cv.h = (f16)v;
        x1w[row * 72 + col] = cv.u;     // reuse region for y2 staging
      }
  }
  __syncthreads();
  { // y2 partial store: 64 rows x 8 chunks = 512 granules
#pragma unroll
    for (int it = 0; it < 2; ++it){
      const int u   = tid + (it << 8);
      const int row = u >> 3, ch = u & 7;
      const f16x8 vv = *(const f16x8*)((const char*)x1w + row * 144 + ch * 16);
      *(f16x8*)(y2s + (size_t)(b0 + row) * 2048 + d * 64 + ch * 8) = vv;
    }
  }
#undef LOADB
#undef COMP
}

// ------- final: out[b, 40:168] = sum_d concat(x1, y2), coalesced reads -------
__global__ __launch_bounds__(128)
void finalize(const f16* __restrict__ x1s, const f16* __restrict__ y2s,
              float* __restrict__ out){
  const int b = blockIdx.x;
  const int t = threadIdx.x;
  if (t < 64){
    float s = 0.f;
#pragma unroll
    for (int d = 0; d < 32; ++d) s += (float)x1s[(size_t)b * 2048 + d * 64 + t];
    out[(size_t)b * 168 + 40 + t] = s;
  } else {
    const int o = t - 64;
    float s = 0.f;
#pragma unroll
    for (int d = 0; d < 32; ++d) s += (float)y2s[(size_t)b * 2048 + d * 64 + o];
    out[(size_t)b * 168 + 104 + o] = s;
  }
}

extern "C" void kernel_launch(void* const* d_in, const int* in_sizes, int n_in,
                              void* d_out, int out_size, void* d_ws, size_t ws_size,
                              hipStream_t stream){
  const float* x   = (const float*)d_in[0];
  const float* W0  = (const float*)d_in[1];
  const float* b0v = (const float*)d_in[2];
  const float* W1  = (const float*)d_in[3];
  const float* b1v = (const float*)d_in[4];
  float* out = (float*)d_out;

  char* ws = (char*)d_ws;
  f16* xt  = (f16*)(ws + 0);            // 32*2048*40*2  =  5,242,880
  f16* W0p = (f16*)(ws + 5242880);      // 32*64*1600*2  =  6,553,600
  f16* W1p = (f16*)(ws + 11796480);     // 32*64*2560*2  = 10,485,760
  f16* x1s = (f16*)(ws + 22282240);     // 2048*32*64*2  =  8,388,608
  f16* y2s = (f16*)(ws + 30670848);     // 2048*32*64*2  =  8,388,608

  prep<<<3080, 256, 0, stream>>>(x, W0, W1, xt, W0p, W1p, out);
  cin_fused<<<1024, 256, 0, stream>>>(xt, W0p, W1p, b0v, b1v, x1s, y2s);
  finalize<<<2048, 128, 0, stream>>>(x1s, y2s, out);
}

// Round 17
// 60.504 us; speedup vs baseline: 1.0392x; 1.0392x over previous
//
#include <hip/hip_runtime.h>

typedef unsigned int   u32;
typedef unsigned short u16;
typedef _Float16       f16;

using f16x8  = __attribute__((ext_vector_type(8)))  _Float16;
using f16x4  = __attribute__((ext_vector_type(4)))  _Float16;
using f32x16 = __attribute__((ext_vector_type(16))) float;

#define KEEP(x) asm volatile("" : "+v"(x))

// ---- merged prep: [bid<2560] x transpose+sums; [else] W0/W1 k-panel ----
__global__ __launch_bounds__(256)
void prep(const float* __restrict__ x,
          const float* __restrict__ W0, const float* __restrict__ W1,
          f16* __restrict__ xt, f16* __restrict__ W0p, f16* __restrict__ W1p,
          float* __restrict__ out){
  __shared__ char shm[33920];
  const int tid = threadIdx.x;
  if (blockIdx.x < 2560){
    float (*tile)[33] = (float(*)[33])shm;
    const int r0 = blockIdx.x << 5;
    const int c  = tid & 31;
    const int rp = tid >> 5;
#pragma unroll
    for (int p = 0; p < 4; ++p){
      const int r = (p << 3) + rp;
      float v = x[(size_t)(r0 + r) * 32 + c];
      tile[r][c] = v;
      float s = v;
#pragma unroll
      for (int off = 16; off > 0; off >>= 1) s += __shfl_xor(s, off, 32);
      if (c == 0){
        const int row = r0 + r;            // = b*40 + f
        out[(size_t)(row / 40) * 168 + (row % 40)] = s;
      }
    }
    __syncthreads();
#pragma unroll
    for (int p = 0; p < 4; ++p){
      const int dd = (p << 3) + rp;
      xt[(size_t)dd * 81920 + r0 + c] = (f16)tile[c][dd];
    }
  } else {
    u16* t = (u16*)shm;
    int kb = blockIdx.x - 2560;
    const float* in; f16* outp; int K;
    if (kb < 200){ in = W0; outp = W0p; K = 1600; }
    else         { kb -= 200; in = W1; outp = W1p; K = 2560; }
    const int kbase = kb << 3;
#pragma unroll 4
    for (int i = 0; i < 64; ++i){
      const int idx = tid + (i << 8);
      const int o   = idx >> 8;
      const int rem = idx & 255;
      const int e   = rem >> 5;
      const int dd  = rem & 31;
      const float v = in[(size_t)o * (K * 32) + (size_t)(kbase + e) * 32 + dd];
      union { f16 h; u16 u; } cv; cv.h = (f16)v;
      t[dd * 530 + o * 8 + e] = cv.u;
    }
    __syncthreads();
    const u32* t32 = (const u32*)t;
    u32* o32 = (u32*)outp;
    const int obase = kb << 8;
#pragma unroll 4
    for (int i = 0; i < 32; ++i){
      const int idx = tid + (i << 8);
      const int dd  = idx >> 8;
      const int rem = idx & 255;
      o32[(size_t)dd * (K * 32) + obase + rem] = t32[dd * 265 + rem];
    }
  }
}

// ---- fused CIN: barrier-free K-split, ZERO-fence fully-unrolled K loops ----
// Block: 64 rows x 64 cols x one d, 4 waves = (wc col-half) x (kh K-half).
// Wave: 64 rows x 32 cols x K/2, BK=80 tiles, B global->regs dbuf,
// ALL x-data (sl slots + xh) preloaded to registers: no LDS, no barriers,
// no sched_barrier/setprio in the K loops -> compiler free to pipeline.
__global__ __launch_bounds__(256, 2)
void cin_fused(const f16* __restrict__ xt,     // [32][2048*40] f16
               const f16* __restrict__ W0p,    // [32][200][64][8] f16
               const f16* __restrict__ W1p,    // [32][320][64][8] f16
               const float* __restrict__ b0v, const float* __restrict__ b1v,
               f16* __restrict__ x1s,          // [2048][32][64] f16
               f16* __restrict__ y2s){         // [2048][32][64] f16
  constexpr int XOFF = 16896;           // red[2][64][33] f32 below; x0/x1 overlay

  const int bid = blockIdx.x;
  const int d   = ((bid & 7) << 2) | ((bid >> 3) & 3);   // XCD-local d groups
  const int b0  = (bid >> 5) << 6;      // 32 b-tiles of 64 rows
  const int tid = threadIdx.x;
  const int wv  = tid >> 6;
  const int kh  = wv >> 1;              // K half
  const int wc  = wv & 1;               // col half (32 cols)
  const int l   = tid & 63;
  const int hi  = l >> 5;               // k-run parity within MFMA
  const int lr  = l & 31;

  __shared__ char smem[26112];

  const f16* gW0 = W0p + (size_t)d * 102400;
  const f16* gW1 = W1p + (size_t)d * 163840;
  const int lane_off = hi * 512 + ((wc << 5) + lr) * 8;  // f16 units

  f16x8 Ba[5], Bb[5];

#define LOADB(B, GP, TT) do { \
    _Pragma("unroll") \
    for (int mi_ = 0; mi_ < 5; ++mi_) \
      (B)[mi_] = *(const f16x8*)((GP) + (size_t)(TT) * 5120 + mi_ * 1024); \
  } while (0)

  const f16* g1 = gW0 + kh * 51200 + lane_off;
  LOADB(Ba, g1, 0);                     // phase-1 tile 0 in flight

  { // stage x0 tile: 64 rows * 80B -> stride 96B
    const uint4* src = (const uint4*)(xt + (size_t)d * 81920 + (size_t)b0 * 40);
#pragma unroll
    for (int it = 0; it < 2; ++it){
      const int idx = tid + (it << 8);
      if (idx < 320){
        const int r = idx / 5, c = idx - r * 5;
        *(uint4*)(smem + XOFF + r * 96 + c * 16) = src[idx];
      }
    }
  }
  __syncthreads();

  const char* x0row = smem + XOFF + lr * 96;    // + m*3072 per strip
  const char* x1row = smem + XOFF + lr * 144;   // + m*4608 per strip
  const int   col = (wc << 5) + lr;
  const float bv1 = b0v[col];
  const float bv2 = b1v[col];

  // sl[m][s] = x0 f-block (s+hi)%5 of strip-m row (pinned in VGPRs)
  f16x8 sl[2][5];
#pragma unroll
  for (int m = 0; m < 2; ++m){
    const char* xe = x0row + m * 3072 + hi * 16;
#pragma unroll
    for (int t = 0; t < 4; ++t) sl[m][t] = *(const f16x8*)(xe + t * 16);
    sl[m][4] = *(const f16x8*)(x0row + m * 3072 + (hi ? 0 : 64));
  }
  KEEP(sl[0][0]); KEEP(sl[0][1]); KEEP(sl[0][2]); KEEP(sl[0][3]); KEEP(sl[0][4]);
  KEEP(sl[1][0]); KEEP(sl[1][1]); KEEP(sl[1][2]); KEEP(sl[1][3]); KEEP(sl[1][4]);

  // phase-1 xh preload: 20 h-values per strip (kh half), 5x f16x4 (8B-aligned)
  f16x4 xq0[5], xq1[5];
#pragma unroll
  for (int q = 0; q < 5; ++q){
    xq0[q] = *(const f16x4*)(x0row + kh * 40 + q * 8);
    xq1[q] = *(const f16x4*)(x0row + 3072 + kh * 40 + q * 8);
    KEEP(xq0[q]); KEEP(xq1[q]);
  }

  const f32x16 fz = {0,0,0,0,0,0,0,0,0,0,0,0,0,0,0,0};
  f32x16 accA = fz, accB = fz;          // strip 0 / strip 1 chains

  // BK=80: MFMA mi uses runs {2mi+hi}; slot (2mi)%5 via hi-rotated sl;
  // h = 2t + (mi<2 ? 0 : mi>2 ? 1 : hi).
  static constexpr int SI[5] = {0, 2, 4, 1, 3};

  // ---------------- phase 1: xk = x0, 10 tiles per wave ----------------
#pragma unroll
  for (int t = 0; t < 10; ++t){
    if (t + 1 < 10){
      if ((t + 1) & 1) { LOADB(Bb, g1, t + 1); } else { LOADB(Ba, g1, t + 1); }
    }
    const int e0 = 2 * t, e1 = 2 * t + 1;
    const f16 a_lo = xq0[e0 >> 2][e0 & 3], a_hi = xq0[e1 >> 2][e1 & 3];
    const f16 b_lo = xq1[e0 >> 2][e0 & 3], b_hi = xq1[e1 >> 2][e1 & 3];
    const f16 am = hi ? a_hi : a_lo;
    const f16 bm = hi ? b_hi : b_lo;
#pragma unroll
    for (int mi = 0; mi < 5; ++mi){
      const f16x8 bf = ((t & 1) ? Bb : Ba)[mi];
      const f16 xa0 = (mi < 2) ? a_lo : (mi > 2) ? a_hi : am;
      const f16 xa1 = (mi < 2) ? b_lo : (mi > 2) ? b_hi : bm;
      accA = __builtin_amdgcn_mfma_f32_32x32x16_f16(sl[0][SI[mi]] * xa0, bf, accA, 0, 0, 0);
      accB = __builtin_amdgcn_mfma_f32_32x32x16_f16(sl[1][SI[mi]] * xa1, bf, accB, 0, 0, 0);
    }
  }

  // ---- phase boundary: kh-reduce, bias+relu, x1 -> LDS + global ----
  const f16* g2 = gW1 + kh * 81920 + lane_off;
  LOADB(Ba, g2, 0);                     // phase-2 tile 0 in flight (overlaps)

  float* redp = (float*)(smem + wc * 8448);     // [64][33] f32 per col-half
  u16*   x1w  = (u16*)(smem + XOFF);            // [64][72] u16 (overlays x0)
  if (kh == 1){
#pragma unroll
    for (int m = 0; m < 2; ++m)
#pragma unroll
      for (int reg = 0; reg < 16; ++reg){
        const int row = (m << 5) + (reg & 3) + ((reg >> 2) << 3) + (hi << 2);
        redp[row * 33 + lr] = (m ? accB[reg] : accA[reg]);
      }
  }
  __syncthreads();
  if (kh == 0){
#pragma unroll
    for (int m = 0; m < 2; ++m)
#pragma unroll
      for (int reg = 0; reg < 16; ++reg){
        const int row = (m << 5) + (reg & 3) + ((reg >> 2) << 3) + (hi << 2);
        float v = (m ? accB[reg] : accA[reg]) + redp[row * 33 + lr] + bv1;
        v = v > 0.f ? v : 0.f;
        union { f16 h; u16 u; } cv; cv.h = (f16)v;
        x1w[row * 72 + col] = cv.u;
      }
  }
  accA = fz; accB = fz;
  __syncthreads();                      // x1 tile complete

  { // x1 partial store: 64 rows x 8 chunks = 512 granules, coalesced 16B
#pragma unroll
    for (int it = 0; it < 2; ++it){
      const int u   = tid + (it << 8);
      const int row = u >> 3, ch = u & 7;
      const f16x8 vv = *(const f16x8*)((const char*)x1w + row * 144 + ch * 16);
      *(f16x8*)(x1s + (size_t)(b0 + row) * 2048 + d * 64 + ch * 8) = vv;
    }
  }

  // phase-2 xh preload: 32 h-values per strip, 4x f16x8 (16B-aligned)
  f16x8 xk0[4], xk1[4];
#pragma unroll
  for (int q = 0; q < 4; ++q){
    xk0[q] = *(const f16x8*)(x1row + kh * 64 + q * 16);
    xk1[q] = *(const f16x8*)(x1row + 4608 + kh * 64 + q * 16);
    KEEP(xk0[q]); KEEP(xk1[q]);
  }

  // ---------------- phase 2: xk = x1, 16 tiles per wave ----------------
#pragma unroll
  for (int t = 0; t < 16; ++t){
    if (t + 1 < 16){
      if ((t + 1) & 1) { LOADB(Bb, g2, t + 1); } else { LOADB(Ba, g2, t + 1); }
    }
    const int e0 = 2 * t, e1 = 2 * t + 1;
    const f16 a_lo = xk0[e0 >> 3][e0 & 7], a_hi = xk0[e1 >> 3][e1 & 7];
    const f16 b_lo = xk1[e0 >> 3][e0 & 7], b_hi = xk1[e1 >> 3][e1 & 7];
    const f16 am = hi ? a_hi : a_lo;
    const f16 bm = hi ? b_hi : b_lo;
#pragma unroll
    for (int mi = 0; mi < 5; ++mi){
      const f16x8 bf = ((t & 1) ? Bb : Ba)[mi];
      const f16 xa0 = (mi < 2) ? a_lo : (mi > 2) ? a_hi : am;
      const f16 xa1 = (mi < 2) ? b_lo : (mi > 2) ? b_hi : bm;
      accA = __builtin_amdgcn_mfma_f32_32x32x16_f16(sl[0][SI[mi]] * xa0, bf, accA, 0, 0, 0);
      accB = __builtin_amdgcn_mfma_f32_32x32x16_f16(sl[1][SI[mi]] * xa1, bf, accB, 0, 0, 0);
    }
  }

  // ---- epilogue 2: kh-reduce, bias+relu, y2 -> LDS -> global ----
  if (kh == 1){
#pragma unroll
    for (int m = 0; m < 2; ++m)
#pragma unroll
      for (int reg = 0; reg < 16; ++reg){
        const int row = (m << 5) + (reg & 3) + ((reg >> 2) << 3) + (hi << 2);
        redp[row * 33 + lr] = (m ? accB[reg] : accA[reg]);
      }
  }
  __syncthreads();
  if (kh == 0){
#pragma unroll
    for (int m = 0; m < 2; ++m)
#pragma unroll
      for (int reg = 0; reg < 16; ++reg){
        const int row = (m << 5) + (reg & 3) + ((reg >> 2) << 3) + (hi << 2);
        float v = (m ? accB[reg] : accA[reg]) + redp[row * 33 + lr] + bv2;
        v = v > 0.f ? v : 0.f;
        union { f16 h; u16 u; } cv; cv.h = (f16)v;
        x1w[row * 72 + col] = cv.u;     // reuse region for y2 staging
      }
  }
  __syncthreads();
  { // y2 partial store: 64 rows x 8 chunks = 512 granules
#pragma unroll
    for (int it = 0; it < 2; ++it){
      const int u   = tid + (it << 8);
      const int row = u >> 3, ch = u & 7;
      const f16x8 vv = *(const f16x8*)((const char*)x1w + row * 144 + ch * 16);
      *(f16x8*)(y2s + (size_t)(b0 + row) * 2048 + d * 64 + ch * 8) = vv;
    }
  }
#undef LOADB
}

// ------- final: out[b, 40:168] = sum_d concat(x1, y2), coalesced reads -------
__global__ __launch_bounds__(128)
void finalize(const f16* __restrict__ x1s, const f16* __restrict__ y2s,
              float* __restrict__ out){
  const int b = blockIdx.x;
  const int t = threadIdx.x;
  if (t < 64){
    float s = 0.f;
#pragma unroll
    for (int d = 0; d < 32; ++d) s += (float)x1s[(size_t)b * 2048 + d * 64 + t];
    out[(size_t)b * 168 + 40 + t] = s;
  } else {
    const int o = t - 64;
    float s = 0.f;
#pragma unroll
    for (int d = 0; d < 32; ++d) s += (float)y2s[(size_t)b * 2048 + d * 64 + o];
    out[(size_t)b * 168 + 104 + o] = s;
  }
}

extern "C" void kernel_launch(void* const* d_in, const int* in_sizes, int n_in,
                              void* d_out, int out_size, void* d_ws, size_t ws_size,
                              hipStream_t stream){
  const float* x   = (const float*)d_in[0];
  const float* W0  = (const float*)d_in[1];
  const float* b0v = (const float*)d_in[2];
  const float* W1  = (const float*)d_in[3];
  const float* b1v = (const float*)d_in[4];
  float* out = (float*)d_out;

  char* ws = (char*)d_ws;
  f16* xt  = (f16*)(ws + 0);            // 32*2048*40*2  =  5,242,880
  f16* W0p = (f16*)(ws + 5242880);      // 32*64*1600*2  =  6,553,600
  f16* W1p = (f16*)(ws + 11796480);     // 32*64*2560*2  = 10,485,760
  f16* x1s = (f16*)(ws + 22282240);     // 2048*32*64*2  =  8,388,608
  f16* y2s = (f16*)(ws + 30670848);     // 2048*32*64*2  =  8,388,608

  prep<<<3080, 256, 0, stream>>>(x, W0, W1, xt, W0p, W1p, out);
  cin_fused<<<1024, 256, 0, stream>>>(xt, W0p, W1p, b0v, b1v, x1s, y2s);
  finalize<<<2048, 128, 0, stream>>>(x1s, y2s, out);
}